// Round 11
// baseline (193.832 us; speedup 1.0000x reference)
//
#include <hip/hip_runtime.h>
#include <hip/hip_fp16.h>
#include <math.h>

// GCN: out = softmax( S·relu((S·h)W1 + b1) · W2 + b2 ),  S = in-edge sum + self-loop.
// Round 21: R20 design with the one-line correctness fix. R20's failure was a
// unit bug: prep wrote the HH zero row via ((float*)(HH + N*64)) with HH typed
// __half2* -> landed at byte N*256 (inside XH), leaving the real zero row at byte
// N*128 poisoned; sentinel gathers then summed garbage. Fix: write in half2 units
// (HH[N*32 + tid]), matching fused1's H4[N*16 + fl] reads exactly.
//  (1) per-node CSR runs padded to x8 with sentinel N + zero rows -> inner gather
//      loops have ZERO predication (no ok/w/clamp/cndmask, no wave-max shuffles).
//  (2) ZH rows packed to 40 halves (80B): gather2 row traffic -37%.

constexpr int N = 100000;
constexpr int E = 1200000;
constexpr int D = 64;    // input dim
constexpr int H = 128;   // hidden
constexpr int C = 40;    // classes
constexpr int NBUCK2 = 98;                      // buckets of 1024 dst nodes
constexpr int EBLK   = 2048;                    // edges per append block
constexpr int NHB    = (E + EBLK - 1) / EBLK;   // 586 edge blocks
constexpr int SCAP   = 16384;                   // staging capacity per bucket
constexpr int CCAP   = 20480;                   // csr capacity per bucket (padded)
constexpr int PREPB  = 1024;                    // prep grid

typedef _Float16 f16x8 __attribute__((ext_vector_type(8)));
typedef float    f32x4 __attribute__((ext_vector_type(4)));

// ---- prep: h->fp16 convert + HH zero row + W1/W2 fragment packs + gcnt zero ----
__global__ __launch_bounds__(256) void prep(const float2* __restrict__ hf,
                                            __half2* __restrict__ HH,
                                            const float* __restrict__ W1,
                                            const float* __restrict__ W2,
                                            f16x8* __restrict__ w1frag,
                                            f16x8* __restrict__ w2frag,
                                            int* __restrict__ gcnt) {
    if (blockIdx.x < 4) {                       // pack W1 -> 1024 frags
        int e = blockIdx.x * 256 + threadIdx.x;
        int l = e & 63, cf = e >> 6;            // cf = ct*2+f
        int f = cf & 1, ct = cf >> 1;
        int kbase = f * 32 + (l >> 4) * 8;
        int c = ct * 16 + (l & 15);
        f16x8 v;
#pragma unroll
        for (int r = 0; r < 8; ++r)
            v[r] = (_Float16)W1[(kbase + r) * H + c];
        w1frag[e] = v;
    } else if (blockIdx.x < 7) {                // pack W2 -> 768 frags (48-col pad)
        int e = (blockIdx.x - 4) * 256 + threadIdx.x;
        int l = e & 63, cf = e >> 6;            // cf = ct*4+kc
        int kc = cf & 3, ct = cf >> 2;
        int kbase = kc * 32 + (l >> 4) * 8;
        int c = ct * 16 + (l & 15);
        f16x8 v;
#pragma unroll
        for (int r = 0; r < 8; ++r)
            v[r] = (c < C) ? (_Float16)W2[(kbase + r) * C + c] : (_Float16)0.f;
        w2frag[e] = v;
    } else if (blockIdx.x == 7 && threadIdx.x < 128) {
        gcnt[threadIdx.x] = 0;
    } else if (blockIdx.x == 8 && threadIdx.x < 32) {
        // HH zero row: half2 units! index N*32 = byte N*128 (the row H4[N*16+fl] reads)
        HH[(size_t)N * 32 + threadIdx.x] = __floats2half2_rn(0.f, 0.f);
    }
    for (int i = blockIdx.x * 256 + threadIdx.x; i < N * 32; i += PREPB * 256) {
        float2 p = hf[i];
        HH[i] = __floats2half2_rn(p.x, p.y);
    }
}

// ---- single-pass append: LDS bucket count -> one global atomicAdd per
//      (block,bucket) -> scatter into bucket staging windows ----
__global__ __launch_bounds__(256) void append_d(const int2* __restrict__ edges,
                                                int* __restrict__ gcnt,
                                                int* __restrict__ staging) {
    __shared__ int lcnt[NBUCK2], lbase[NBUCK2];
    int t = threadIdx.x;
    if (t < NBUCK2) lcnt[t] = 0;
    __syncthreads();
    int base = blockIdx.x * EBLK + t * 8;
    int2 ed[8]; int pos[8];
#pragma unroll
    for (int i = 0; i < 8; ++i) {
        int e = base + i;
        if (e < E) {
            ed[i] = edges[e];
            pos[i] = atomicAdd(&lcnt[ed[i].y >> 10], 1);   // LDS atomic
        }
    }
    __syncthreads();
    if (t < NBUCK2 && lcnt[t]) lbase[t] = atomicAdd(&gcnt[t], lcnt[t]);
    __syncthreads();
#pragma unroll
    for (int i = 0; i < 8; ++i) {
        int e = base + i;
        if (e < E) {
            int b = ed[i].y >> 10;
            int p = lbase[b] + pos[i];
            if (p < SCAP)                                   // never in practice
                staging[b * SCAP + p] = (ed[i].x << 10) | (ed[i].y & 1023);
        }
    }
}

// ---- per-bucket: LDS count -> wave-scan of PADDED lengths -> rd, sentinel pad,
//      scatter csr. Node window = x8-padded; pad slots = N (zero row). ----
__global__ __launch_bounds__(1024) void fill_b(const int* __restrict__ staging,
                                               const int* __restrict__ gcnt,
                                               int2* __restrict__ rd,
                                               int* __restrict__ csr) {
    __shared__ int cnt[1024], cur[1024], wtot[16], wbase[16];
    int b = blockIdx.x, t = threadIdx.x;
    cnt[t] = 0;
    __syncthreads();
    int tot = gcnt[b];
    if (tot > SCAP) tot = SCAP;
    int lo_s = b * SCAP;
    for (int i = t; i < tot; i += 1024)
        atomicAdd(&cnt[staging[lo_s + i] & 1023], 1);
    __syncthreads();
    int v = cnt[t];
    int vp = (v + 7) & ~7;                       // padded length
    int lane = t & 63, wid = t >> 6;
    int sv = vp;                                 // inclusive wave scan of vp
#pragma unroll
    for (int off = 1; off < 64; off <<= 1) {
        int x = __shfl_up(sv, off);
        if (lane >= off) sv += x;
    }
    if (lane == 63) wtot[wid] = sv;
    __syncthreads();
    if (t == 0) {
        int run = 0;
#pragma unroll
        for (int i = 0; i < 16; ++i) { wbase[i] = run; run += wtot[i]; }
    }
    __syncthreads();
    int ex = sv - vp + wbase[wid];
    cur[t] = ex;
    int lo_c = b * CCAP;
    int node = (b << 10) + t;
    if (node < N) rd[node] = make_int2(lo_c + ex, v);
    for (int j = v; j < vp; ++j) csr[lo_c + ex + j] = N;   // sentinel pad
    __syncthreads();
    for (int i = t; i < tot; i += 1024) {
        int w = staging[lo_s + i];
        int p = atomicAdd(&cur[w & 1023], 1);
        csr[lo_c + p] = w >> 10;
    }
}

// ---- FUSED layer 1: gather (4 nodes/wave, 16 lanes/node, batch-8,
//      predication-FREE via sentinel pad + zero row) -> LDS -> MFMA ----
__global__ __launch_bounds__(256) void fused1(const __half2* __restrict__ HH,
                                              const int* __restrict__ csr,
                                              const int2* __restrict__ rd,
                                              const f16x8* __restrict__ wfrag,
                                              const float* __restrict__ b1,
                                              __half* __restrict__ XH) {
    __shared__ _Float16 a_h[16 * 72] __attribute__((aligned(16)));
    int nl = threadIdx.x >> 4;                 // node-local 0..15
    int fl = threadIdx.x & 15;
    int node = blockIdx.x * 16 + nl;
    const float2* H4 = (const float2*)HH;      // row = 16 float2 = 128 B
    int2 rdv = rd[node];
    int rs = rdv.x;
    int dpad = (rdv.y + 7) & ~7;               // x8-padded run length
    float a0, a1, a2, a3;
    {   // self-loop init
        float2 raw = H4[node * 16 + fl];
        const __half2* hp = (const __half2*)&raw;
        float2 v0 = __half22float2(hp[0]), v1 = __half22float2(hp[1]);
        a0 = v0.x; a1 = v0.y; a2 = v1.x; a3 = v1.y;
    }
    for (int j0 = 0; j0 < dpad; j0 += 8) {     // 8 rows in flight, no predication
        int k[8];
#pragma unroll
        for (int t = 0; t < 8; ++t) k[t] = csr[rs + j0 + t];
#pragma unroll
        for (int t = 0; t < 8; ++t) {
            float2 raw = H4[k[t] * 16 + fl];   // sentinel -> zero row (L1-hot)
            const __half2* hp = (const __half2*)&raw;
            float2 v0 = __half22float2(hp[0]), v1 = __half22float2(hp[1]);
            a0 += v0.x; a1 += v0.y; a2 += v1.x; a3 += v1.y;
        }
    }
    *(__half2*)&a_h[nl * 72 + fl * 4]     = __floats2half2_rn(a0, a1);
    *(__half2*)&a_h[nl * 72 + fl * 4 + 2] = __floats2half2_rn(a2, a3);
    __syncthreads();
    // ---- MFMA phase: wave wv -> col tiles t0=2wv, t1=2wv+1 ----
    int wv = threadIdx.x >> 6;
    int l  = threadIdx.x & 63;
    int lg = l >> 4, lr = l & 15;
    f16x8 aA0 = *(const f16x8*)&a_h[lr * 72 + 0 * 32 + lg * 8];
    f16x8 aA1 = *(const f16x8*)&a_h[lr * 72 + 1 * 32 + lg * 8];
    int t0 = wv * 2, t1 = wv * 2 + 1;
    f16x8 b00 = wfrag[(t0 * 2 + 0) * 64 + l];
    f16x8 b01 = wfrag[(t0 * 2 + 1) * 64 + l];
    f16x8 b10 = wfrag[(t1 * 2 + 0) * 64 + l];
    f16x8 b11 = wfrag[(t1 * 2 + 1) * 64 + l];
    f32x4 acc0 = {0.f, 0.f, 0.f, 0.f}, acc1 = {0.f, 0.f, 0.f, 0.f};
    acc0 = __builtin_amdgcn_mfma_f32_16x16x32_f16(aA0, b00, acc0, 0, 0, 0);
    acc0 = __builtin_amdgcn_mfma_f32_16x16x32_f16(aA1, b01, acc0, 0, 0, 0);
    acc1 = __builtin_amdgcn_mfma_f32_16x16x32_f16(aA0, b10, acc1, 0, 0, 0);
    acc1 = __builtin_amdgcn_mfma_f32_16x16x32_f16(aA1, b11, acc1, 0, 0, 0);
    // ---- epilogue: D col = lane&15, row = (lane>>4)*4 + r (verified layout) ----
    int row0 = blockIdx.x * 16;
    int c0 = t0 * 16 + lr, c1 = t1 * 16 + lr;
    float bias0 = b1[c0], bias1 = b1[c1];
#pragma unroll
    for (int r = 0; r < 4; ++r) {
        int row = row0 + lg * 4 + r;
        XH[row * H + c0] = __float2half_rn(fmaxf(acc0[r] + bias0, 0.f));
        XH[row * H + c1] = __float2half_rn(fmaxf(acc1[r] + bias1, 0.f));
    }
}

// ---- gemm2 via MFMA: ZH (PACKED 40 halves/row) = XH @ W2; + ZH zero row ----
constexpr int X2S = 136;   // padded LDS stride (halves): 2-way conflict = free
__global__ __launch_bounds__(256) void gemm2(const __half* __restrict__ XH,
                                             const f16x8* __restrict__ w2frag,
                                             __half* __restrict__ ZH) {
    __shared__ _Float16 x_h[64 * X2S] __attribute__((aligned(16)));
    int row0 = blockIdx.x * 64;
    if (blockIdx.x == 0 && threadIdx.x < 20)
        ((float*)(ZH + (size_t)N * 40))[threadIdx.x] = 0.f;   // ZH zero row (80 B; ZH is __half*)
    // stage XH raw fp16: 1024 chunks of 8 halves
#pragma unroll
    for (int i = 0; i < 4; ++i) {
        int idx = threadIdx.x + i * 256;
        int r = idx >> 4, q = idx & 15;
        int grow = row0 + r;
        if (grow >= N) grow = N - 1;
        *(f16x8*)&x_h[r * X2S + q * 8] = *(const f16x8*)&XH[grow * H + q * 8];
    }
    __syncthreads();
    int wv = threadIdx.x >> 6;            // wave -> rows wv*16..+15
    int l  = threadIdx.x & 63;
    int lg = l >> 4, lr = l & 15;
    f16x8 a[4];
#pragma unroll
    for (int kc = 0; kc < 4; ++kc)
        a[kc] = *(const f16x8*)&x_h[(wv * 16 + lr) * X2S + kc * 32 + lg * 8];
#pragma unroll
    for (int ct = 0; ct < 3; ++ct) {
        f32x4 acc = {0.f, 0.f, 0.f, 0.f};
#pragma unroll
        for (int kc = 0; kc < 4; ++kc)
            acc = __builtin_amdgcn_mfma_f32_16x16x32_f16(a[kc],
                      w2frag[(ct * 4 + kc) * 64 + l], acc, 0, 0, 0);
        int col = ct * 16 + lr;
        if (col < C) {
#pragma unroll
            for (int r = 0; r < 4; ++r) {
                int row = row0 + wv * 16 + lg * 4 + r;
                if (row < N) ZH[(size_t)row * 40 + col] = __float2half_rn(acc[r]);
            }
        }
    }
}

// ---- out[node] = softmax(Z[node] + sum Z[src] + b2): packed 80B rows,
//      predication-free batch-8 via sentinel pad + zero row ----
__global__ __launch_bounds__(256) void gather2_softmax(const __half2* __restrict__ ZH,
                                                       const int* __restrict__ csr,
                                                       const int2* __restrict__ rd,
                                                       const float* __restrict__ b2,
                                                       float4* __restrict__ out) {
    int node = blockIdx.x * 16 + (threadIdx.x >> 4);
    int fl = threadIdx.x & 15;
    const float2* Z4 = (const float2*)ZH;     // packed row = 10 float2 = 80 B
    int2 rdv = rd[node];
    int rs = rdv.x;
    int dpad = (rdv.y + 7) & ~7;
    bool real = fl < 10;
    float a0 = 0.f, a1 = 0.f, a2 = 0.f, a3 = 0.f;
    if (real) {   // self-loop init
        float2 raw = Z4[node * 10 + fl];
        const __half2* hp = (const __half2*)&raw;
        float2 v0 = __half22float2(hp[0]), v1 = __half22float2(hp[1]);
        a0 = v0.x; a1 = v0.y; a2 = v1.x; a3 = v1.y;
    }
    for (int j0 = 0; j0 < dpad; j0 += 8) {
        int k[8];
#pragma unroll
        for (int t = 0; t < 8; ++t) k[t] = csr[rs + j0 + t];
        if (real) {
#pragma unroll
            for (int t = 0; t < 8; ++t) {
                float2 raw = Z4[k[t] * 10 + fl];   // sentinel -> zero row
                const __half2* hp = (const __half2*)&raw;
                float2 v0 = __half22float2(hp[0]), v1 = __half22float2(hp[1]);
                a0 += v0.x; a1 += v0.y; a2 += v1.x; a3 += v1.y;
            }
        }
    }
    // softmax over the 40 real cols (lanes fl<10, cols 4fl..4fl+3)
    const float4* b4 = (const float4*)b2;
    float4 bb = b4[real ? fl : 9];
    float v0 = real ? a0 + bb.x : -INFINITY;
    float v1 = real ? a1 + bb.y : -INFINITY;
    float v2 = real ? a2 + bb.z : -INFINITY;
    float v3 = real ? a3 + bb.w : -INFINITY;
    float m = fmaxf(fmaxf(v0, v1), fmaxf(v2, v3));
#pragma unroll
    for (int off = 1; off < 16; off <<= 1) m = fmaxf(m, __shfl_xor(m, off));
    float e0 = __expf(v0 - m), e1 = __expf(v1 - m);   // -inf lanes -> exp = 0
    float e2 = __expf(v2 - m), e3 = __expf(v3 - m);
    float s = (e0 + e1) + (e2 + e3);
#pragma unroll
    for (int off = 1; off < 16; off <<= 1) s += __shfl_xor(s, off);
    float inv = 1.f / s;
    if (real)
        out[node * 10 + fl] = make_float4(e0 * inv, e1 * inv, e2 * inv, e3 * inv);
}

extern "C" void kernel_launch(void* const* d_in, const int* in_sizes, int n_in,
                              void* d_out, int out_size, void* d_ws, size_t ws_size,
                              hipStream_t stream) {
    const float* h   = (const float*)d_in[0];   // N*D
    const int*   adj = (const int*)  d_in[1];   // E*2
    const float* W1  = (const float*)d_in[2];   // D*H
    const float* b1  = (const float*)d_in[3];   // H
    const float* W2  = (const float*)d_in[4];   // H*C
    const float* b2  = (const float*)d_in[5];   // C
    float* out = (float*)d_out;                 // N*C fp32

    // workspace (~62 MB), NO aliasing:
    //   w1frag 16KB | w2frag 12KB | HH (N+1)*64 | XH N*128 | ZH (N+1 rows x 40)
    //   | gcnt 128 | staging 98*16384 | csr 98*20480 | rd N int2
    f16x8*  w1frag = (f16x8*)d_ws;                       // 1024 x 16 B
    f16x8*  w2frag = w1frag + 1024;                      // 768 x 16 B
    __half* HH = (__half*)(w2frag + 768);                // (N+1)*64 fp16
    __half* XH = HH + (size_t)(N + 1) * 64;              // N*128 fp16
    __half* ZH = XH + (size_t)N * H;                     // (N+1)*40 fp16 packed
    int* gcnt    = (int*)(ZH + (size_t)(N + 1) * 40);    // 128
    int* staging = gcnt + 128;                           // NBUCK2*SCAP
    int* csr     = staging + NBUCK2 * SCAP;              // NBUCK2*CCAP
    int2* rd     = (int2*)(csr + NBUCK2 * CCAP);         // N (row_start, deg)

    prep     <<<PREPB, 256, 0, stream>>>((const float2*)h, (__half2*)HH,
                                         W1, W2, w1frag, w2frag, gcnt);
    append_d <<<NHB, 256, 0, stream>>>((const int2*)adj, gcnt, staging);
    fill_b   <<<NBUCK2, 1024, 0, stream>>>(staging, gcnt, rd, csr);

    fused1         <<<N / 16, 256, 0, stream>>>((const __half2*)HH, csr, rd,
                                                w1frag, b1, XH);
    gemm2          <<<(N + 63) / 64, 256, 0, stream>>>(XH, w2frag, ZH);
    gather2_softmax<<<N / 16, 256, 0, stream>>>((const __half2*)ZH, csr, rd,
                                                b2, (float4*)out);
}

// Round 12
// 190.229 us; speedup vs baseline: 1.0189x; 1.0189x over previous
//
#include <hip/hip_runtime.h>
#include <hip/hip_fp16.h>
#include <math.h>

// GCN: out = softmax( S·relu((S·h)W1 + b1) · W2 + b2 ),  S = in-edge sum + self-loop.
// Round 22: best-of-both. R21's 80B-packed ZH rows straddled cache lines (random
// row gathers fetch LINES, not bytes -> ~1.6x traffic) and regressed. Keep R21's
// sentinel-padded predication-free gather loops + correct zero rows; restore
// R19's 128B-aligned 64-half ZH rows. gather2 reads only the 10 real lanes
// (80B of a line-aligned row = 1 line fetched, the floor); gemm2 writes cols
// 0..39 only (cols 40..63 never read; zero row spans the full 128B).

constexpr int N = 100000;
constexpr int E = 1200000;
constexpr int D = 64;    // input dim
constexpr int H = 128;   // hidden
constexpr int C = 40;    // classes
constexpr int NBUCK2 = 98;                      // buckets of 1024 dst nodes
constexpr int EBLK   = 2048;                    // edges per append block
constexpr int NHB    = (E + EBLK - 1) / EBLK;   // 586 edge blocks
constexpr int SCAP   = 16384;                   // staging capacity per bucket
constexpr int CCAP   = 20480;                   // csr capacity per bucket (padded)
constexpr int PREPB  = 1024;                    // prep grid

typedef _Float16 f16x8 __attribute__((ext_vector_type(8)));
typedef float    f32x4 __attribute__((ext_vector_type(4)));

// ---- prep: h->fp16 convert + HH zero row + W1/W2 fragment packs + gcnt zero ----
__global__ __launch_bounds__(256) void prep(const float2* __restrict__ hf,
                                            __half2* __restrict__ HH,
                                            const float* __restrict__ W1,
                                            const float* __restrict__ W2,
                                            f16x8* __restrict__ w1frag,
                                            f16x8* __restrict__ w2frag,
                                            int* __restrict__ gcnt) {
    if (blockIdx.x < 4) {                       // pack W1 -> 1024 frags
        int e = blockIdx.x * 256 + threadIdx.x;
        int l = e & 63, cf = e >> 6;            // cf = ct*2+f
        int f = cf & 1, ct = cf >> 1;
        int kbase = f * 32 + (l >> 4) * 8;
        int c = ct * 16 + (l & 15);
        f16x8 v;
#pragma unroll
        for (int r = 0; r < 8; ++r)
            v[r] = (_Float16)W1[(kbase + r) * H + c];
        w1frag[e] = v;
    } else if (blockIdx.x < 7) {                // pack W2 -> 768 frags (48-col pad)
        int e = (blockIdx.x - 4) * 256 + threadIdx.x;
        int l = e & 63, cf = e >> 6;            // cf = ct*4+kc
        int kc = cf & 3, ct = cf >> 2;
        int kbase = kc * 32 + (l >> 4) * 8;
        int c = ct * 16 + (l & 15);
        f16x8 v;
#pragma unroll
        for (int r = 0; r < 8; ++r)
            v[r] = (c < C) ? (_Float16)W2[(kbase + r) * C + c] : (_Float16)0.f;
        w2frag[e] = v;
    } else if (blockIdx.x == 7 && threadIdx.x < 128) {
        gcnt[threadIdx.x] = 0;
    } else if (blockIdx.x == 8 && threadIdx.x < 32) {
        // HH zero row in half2 units: index N*32 = byte N*128 (what H4[N*16+fl] reads)
        HH[(size_t)N * 32 + threadIdx.x] = __floats2half2_rn(0.f, 0.f);
    }
    for (int i = blockIdx.x * 256 + threadIdx.x; i < N * 32; i += PREPB * 256) {
        float2 p = hf[i];
        HH[i] = __floats2half2_rn(p.x, p.y);
    }
}

// ---- single-pass append: LDS bucket count -> one global atomicAdd per
//      (block,bucket) -> scatter into bucket staging windows ----
__global__ __launch_bounds__(256) void append_d(const int2* __restrict__ edges,
                                                int* __restrict__ gcnt,
                                                int* __restrict__ staging) {
    __shared__ int lcnt[NBUCK2], lbase[NBUCK2];
    int t = threadIdx.x;
    if (t < NBUCK2) lcnt[t] = 0;
    __syncthreads();
    int base = blockIdx.x * EBLK + t * 8;
    int2 ed[8]; int pos[8];
#pragma unroll
    for (int i = 0; i < 8; ++i) {
        int e = base + i;
        if (e < E) {
            ed[i] = edges[e];
            pos[i] = atomicAdd(&lcnt[ed[i].y >> 10], 1);   // LDS atomic
        }
    }
    __syncthreads();
    if (t < NBUCK2 && lcnt[t]) lbase[t] = atomicAdd(&gcnt[t], lcnt[t]);
    __syncthreads();
#pragma unroll
    for (int i = 0; i < 8; ++i) {
        int e = base + i;
        if (e < E) {
            int b = ed[i].y >> 10;
            int p = lbase[b] + pos[i];
            if (p < SCAP)                                   // never in practice
                staging[b * SCAP + p] = (ed[i].x << 10) | (ed[i].y & 1023);
        }
    }
}

// ---- per-bucket: LDS count -> wave-scan of PADDED lengths -> rd, sentinel pad,
//      scatter csr. Node window = x8-padded; pad slots = N (zero row). ----
__global__ __launch_bounds__(1024) void fill_b(const int* __restrict__ staging,
                                               const int* __restrict__ gcnt,
                                               int2* __restrict__ rd,
                                               int* __restrict__ csr) {
    __shared__ int cnt[1024], cur[1024], wtot[16], wbase[16];
    int b = blockIdx.x, t = threadIdx.x;
    cnt[t] = 0;
    __syncthreads();
    int tot = gcnt[b];
    if (tot > SCAP) tot = SCAP;
    int lo_s = b * SCAP;
    for (int i = t; i < tot; i += 1024)
        atomicAdd(&cnt[staging[lo_s + i] & 1023], 1);
    __syncthreads();
    int v = cnt[t];
    int vp = (v + 7) & ~7;                       // padded length
    int lane = t & 63, wid = t >> 6;
    int sv = vp;                                 // inclusive wave scan of vp
#pragma unroll
    for (int off = 1; off < 64; off <<= 1) {
        int x = __shfl_up(sv, off);
        if (lane >= off) sv += x;
    }
    if (lane == 63) wtot[wid] = sv;
    __syncthreads();
    if (t == 0) {
        int run = 0;
#pragma unroll
        for (int i = 0; i < 16; ++i) { wbase[i] = run; run += wtot[i]; }
    }
    __syncthreads();
    int ex = sv - vp + wbase[wid];
    cur[t] = ex;
    int lo_c = b * CCAP;
    int node = (b << 10) + t;
    if (node < N) rd[node] = make_int2(lo_c + ex, v);
    for (int j = v; j < vp; ++j) csr[lo_c + ex + j] = N;   // sentinel pad
    __syncthreads();
    for (int i = t; i < tot; i += 1024) {
        int w = staging[lo_s + i];
        int p = atomicAdd(&cur[w & 1023], 1);
        csr[lo_c + p] = w >> 10;
    }
}

// ---- FUSED layer 1: gather (4 nodes/wave, 16 lanes/node, batch-8,
//      predication-FREE via sentinel pad + zero row) -> LDS -> MFMA ----
__global__ __launch_bounds__(256) void fused1(const __half2* __restrict__ HH,
                                              const int* __restrict__ csr,
                                              const int2* __restrict__ rd,
                                              const f16x8* __restrict__ wfrag,
                                              const float* __restrict__ b1,
                                              __half* __restrict__ XH) {
    __shared__ _Float16 a_h[16 * 72] __attribute__((aligned(16)));
    int nl = threadIdx.x >> 4;                 // node-local 0..15
    int fl = threadIdx.x & 15;
    int node = blockIdx.x * 16 + nl;
    const float2* H4 = (const float2*)HH;      // row = 16 float2 = 128 B
    int2 rdv = rd[node];
    int rs = rdv.x;
    int dpad = (rdv.y + 7) & ~7;               // x8-padded run length
    float a0, a1, a2, a3;
    {   // self-loop init
        float2 raw = H4[node * 16 + fl];
        const __half2* hp = (const __half2*)&raw;
        float2 v0 = __half22float2(hp[0]), v1 = __half22float2(hp[1]);
        a0 = v0.x; a1 = v0.y; a2 = v1.x; a3 = v1.y;
    }
    for (int j0 = 0; j0 < dpad; j0 += 8) {     // 8 rows in flight, no predication
        int k[8];
#pragma unroll
        for (int t = 0; t < 8; ++t) k[t] = csr[rs + j0 + t];
#pragma unroll
        for (int t = 0; t < 8; ++t) {
            float2 raw = H4[k[t] * 16 + fl];   // sentinel -> zero row (L1-hot)
            const __half2* hp = (const __half2*)&raw;
            float2 v0 = __half22float2(hp[0]), v1 = __half22float2(hp[1]);
            a0 += v0.x; a1 += v0.y; a2 += v1.x; a3 += v1.y;
        }
    }
    *(__half2*)&a_h[nl * 72 + fl * 4]     = __floats2half2_rn(a0, a1);
    *(__half2*)&a_h[nl * 72 + fl * 4 + 2] = __floats2half2_rn(a2, a3);
    __syncthreads();
    // ---- MFMA phase: wave wv -> col tiles t0=2wv, t1=2wv+1 ----
    int wv = threadIdx.x >> 6;
    int l  = threadIdx.x & 63;
    int lg = l >> 4, lr = l & 15;
    f16x8 aA0 = *(const f16x8*)&a_h[lr * 72 + 0 * 32 + lg * 8];
    f16x8 aA1 = *(const f16x8*)&a_h[lr * 72 + 1 * 32 + lg * 8];
    int t0 = wv * 2, t1 = wv * 2 + 1;
    f16x8 b00 = wfrag[(t0 * 2 + 0) * 64 + l];
    f16x8 b01 = wfrag[(t0 * 2 + 1) * 64 + l];
    f16x8 b10 = wfrag[(t1 * 2 + 0) * 64 + l];
    f16x8 b11 = wfrag[(t1 * 2 + 1) * 64 + l];
    f32x4 acc0 = {0.f, 0.f, 0.f, 0.f}, acc1 = {0.f, 0.f, 0.f, 0.f};
    acc0 = __builtin_amdgcn_mfma_f32_16x16x32_f16(aA0, b00, acc0, 0, 0, 0);
    acc0 = __builtin_amdgcn_mfma_f32_16x16x32_f16(aA1, b01, acc0, 0, 0, 0);
    acc1 = __builtin_amdgcn_mfma_f32_16x16x32_f16(aA0, b10, acc1, 0, 0, 0);
    acc1 = __builtin_amdgcn_mfma_f32_16x16x32_f16(aA1, b11, acc1, 0, 0, 0);
    // ---- epilogue: D col = lane&15, row = (lane>>4)*4 + r (verified layout) ----
    int row0 = blockIdx.x * 16;
    int c0 = t0 * 16 + lr, c1 = t1 * 16 + lr;
    float bias0 = b1[c0], bias1 = b1[c1];
#pragma unroll
    for (int r = 0; r < 4; ++r) {
        int row = row0 + lg * 4 + r;
        XH[row * H + c0] = __float2half_rn(fmaxf(acc0[r] + bias0, 0.f));
        XH[row * H + c1] = __float2half_rn(fmaxf(acc1[r] + bias1, 0.f));
    }
}

// ---- gemm2 via MFMA: ZH rows = 64 halves (128B aligned), cols 0..39 written,
//      cols 40..63 never read; + full 128B zero row at index N ----
constexpr int X2S = 136;   // padded LDS stride (halves): 2-way conflict = free
__global__ __launch_bounds__(256) void gemm2(const __half* __restrict__ XH,
                                             const f16x8* __restrict__ w2frag,
                                             __half* __restrict__ ZH) {
    __shared__ _Float16 x_h[64 * X2S] __attribute__((aligned(16)));
    int row0 = blockIdx.x * 64;
    if (blockIdx.x == 0 && threadIdx.x < 32)
        ((float*)(ZH + (size_t)N * 64))[threadIdx.x] = 0.f;   // zero row (ZH __half*: byte N*128)
    // stage XH raw fp16: 1024 chunks of 8 halves
#pragma unroll
    for (int i = 0; i < 4; ++i) {
        int idx = threadIdx.x + i * 256;
        int r = idx >> 4, q = idx & 15;
        int grow = row0 + r;
        if (grow >= N) grow = N - 1;
        *(f16x8*)&x_h[r * X2S + q * 8] = *(const f16x8*)&XH[grow * H + q * 8];
    }
    __syncthreads();
    int wv = threadIdx.x >> 6;            // wave -> rows wv*16..+15
    int l  = threadIdx.x & 63;
    int lg = l >> 4, lr = l & 15;
    f16x8 a[4];
#pragma unroll
    for (int kc = 0; kc < 4; ++kc)
        a[kc] = *(const f16x8*)&x_h[(wv * 16 + lr) * X2S + kc * 32 + lg * 8];
#pragma unroll
    for (int ct = 0; ct < 3; ++ct) {
        f32x4 acc = {0.f, 0.f, 0.f, 0.f};
#pragma unroll
        for (int kc = 0; kc < 4; ++kc)
            acc = __builtin_amdgcn_mfma_f32_16x16x32_f16(a[kc],
                      w2frag[(ct * 4 + kc) * 64 + l], acc, 0, 0, 0);
        int col = ct * 16 + lr;
        if (col < C) {
#pragma unroll
            for (int r = 0; r < 4; ++r) {
                int row = row0 + wv * 16 + lg * 4 + r;
                if (row < N) ZH[(size_t)row * 64 + col] = __float2half_rn(acc[r]);
            }
        }
    }
}

// ---- out[node] = softmax(Z[node] + sum Z[src] + b2): 128B-aligned rows,
//      only the 10 real lanes load (80B of the line = 1 line fetched),
//      predication-free batch-8 via sentinel pad + zero row ----
__global__ __launch_bounds__(256) void gather2_softmax(const __half2* __restrict__ ZH,
                                                       const int* __restrict__ csr,
                                                       const int2* __restrict__ rd,
                                                       const float* __restrict__ b2,
                                                       float4* __restrict__ out) {
    int node = blockIdx.x * 16 + (threadIdx.x >> 4);
    int fl = threadIdx.x & 15;
    const float2* Z4 = (const float2*)ZH;     // row = 16 float2 = 128 B
    int2 rdv = rd[node];
    int rs = rdv.x;
    int dpad = (rdv.y + 7) & ~7;
    bool real = fl < 10;
    float a0 = 0.f, a1 = 0.f, a2 = 0.f, a3 = 0.f;
    if (real) {   // self-loop init
        float2 raw = Z4[node * 16 + fl];
        const __half2* hp = (const __half2*)&raw;
        float2 v0 = __half22float2(hp[0]), v1 = __half22float2(hp[1]);
        a0 = v0.x; a1 = v0.y; a2 = v1.x; a3 = v1.y;
    }
    for (int j0 = 0; j0 < dpad; j0 += 8) {
        int k[8];
#pragma unroll
        for (int t = 0; t < 8; ++t) k[t] = csr[rs + j0 + t];
        if (real) {
#pragma unroll
            for (int t = 0; t < 8; ++t) {
                float2 raw = Z4[k[t] * 16 + fl];   // sentinel -> zero row
                const __half2* hp = (const __half2*)&raw;
                float2 v0 = __half22float2(hp[0]), v1 = __half22float2(hp[1]);
                a0 += v0.x; a1 += v0.y; a2 += v1.x; a3 += v1.y;
            }
        }
    }
    // softmax over the 40 real cols (lanes fl<10, cols 4fl..4fl+3)
    const float4* b4 = (const float4*)b2;
    float4 bb = b4[real ? fl : 9];
    float v0 = real ? a0 + bb.x : -INFINITY;
    float v1 = real ? a1 + bb.y : -INFINITY;
    float v2 = real ? a2 + bb.z : -INFINITY;
    float v3 = real ? a3 + bb.w : -INFINITY;
    float m = fmaxf(fmaxf(v0, v1), fmaxf(v2, v3));
#pragma unroll
    for (int off = 1; off < 16; off <<= 1) m = fmaxf(m, __shfl_xor(m, off));
    float e0 = __expf(v0 - m), e1 = __expf(v1 - m);   // -inf lanes -> exp = 0
    float e2 = __expf(v2 - m), e3 = __expf(v3 - m);
    float s = (e0 + e1) + (e2 + e3);
#pragma unroll
    for (int off = 1; off < 16; off <<= 1) s += __shfl_xor(s, off);
    float inv = 1.f / s;
    if (real)
        out[node * 10 + fl] = make_float4(e0 * inv, e1 * inv, e2 * inv, e3 * inv);
}

extern "C" void kernel_launch(void* const* d_in, const int* in_sizes, int n_in,
                              void* d_out, int out_size, void* d_ws, size_t ws_size,
                              hipStream_t stream) {
    const float* h   = (const float*)d_in[0];   // N*D
    const int*   adj = (const int*)  d_in[1];   // E*2
    const float* W1  = (const float*)d_in[2];   // D*H
    const float* b1  = (const float*)d_in[3];   // H
    const float* W2  = (const float*)d_in[4];   // H*C
    const float* b2  = (const float*)d_in[5];   // C
    float* out = (float*)d_out;                 // N*C fp32

    // workspace (~66 MB), NO aliasing:
    //   w1frag 16KB | w2frag 12KB | HH (N+1)*64 | XH N*128 | ZH (N+1)*64 |
    //   gcnt 128 | staging 98*16384 | csr 98*20480 | rd N int2
    f16x8*  w1frag = (f16x8*)d_ws;                       // 1024 x 16 B
    f16x8*  w2frag = w1frag + 1024;                      // 768 x 16 B
    __half* HH = (__half*)(w2frag + 768);                // (N+1)*64 fp16
    __half* XH = HH + (size_t)(N + 1) * 64;              // N*128 fp16
    __half* ZH = XH + (size_t)N * H;                     // (N+1)*64 fp16
    int* gcnt    = (int*)(ZH + (size_t)(N + 1) * 64);    // 128
    int* staging = gcnt + 128;                           // NBUCK2*SCAP
    int* csr     = staging + NBUCK2 * SCAP;              // NBUCK2*CCAP
    int2* rd     = (int2*)(csr + NBUCK2 * CCAP);         // N (row_start, deg)

    prep     <<<PREPB, 256, 0, stream>>>((const float2*)h, (__half2*)HH,
                                         W1, W2, w1frag, w2frag, gcnt);
    append_d <<<NHB, 256, 0, stream>>>((const int2*)adj, gcnt, staging);
    fill_b   <<<NBUCK2, 1024, 0, stream>>>(staging, gcnt, rd, csr);

    fused1         <<<N / 16, 256, 0, stream>>>((const __half2*)HH, csr, rd,
                                                w1frag, b1, XH);
    gemm2          <<<(N + 63) / 64, 256, 0, stream>>>(XH, w2frag, ZH);
    gather2_softmax<<<N / 16, 256, 0, stream>>>((const __half2*)ZH, csr, rd,
                                                b2, (float4*)out);
}

// Round 13
// 179.082 us; speedup vs baseline: 1.0824x; 1.0622x over previous
//
#include <hip/hip_runtime.h>
#include <hip/hip_fp16.h>
#include <math.h>

// GCN: out = softmax( S·relu((S·h)W1 + b1) · W2 + b2 ),  S = in-edge sum + self-loop.
// Round 23: R22 + gemm2 FUSED INTO fused1 (block-local dependency: block b's XH
// rows 16b..16b+15 are produced and consumed in the same block). XH tile goes to
// a 4.4KB LDS buffer (stride 136 halves, 2-way-free) instead of HBM; waves 0-2
// then each run one 16-col ZH tile (4 MFMAs, K=128, same w2frag packing).
// Deletes XH entirely (51MB round-trip) + the gemm2 launch. Bit-identical
// numerics (XH was fp16 in HBM; now fp16 in LDS). ZH zero row moves to prep
// (written in half2 units — R20's unit-bug lesson). Launches 6 -> 5.

constexpr int N = 100000;
constexpr int E = 1200000;
constexpr int D = 64;    // input dim
constexpr int H = 128;   // hidden
constexpr int C = 40;    // classes
constexpr int NBUCK2 = 98;                      // buckets of 1024 dst nodes
constexpr int EBLK   = 2048;                    // edges per append block
constexpr int NHB    = (E + EBLK - 1) / EBLK;   // 586 edge blocks
constexpr int SCAP   = 16384;                   // staging capacity per bucket
constexpr int CCAP   = 20480;                   // csr capacity per bucket (padded)
constexpr int PREPB  = 1024;                    // prep grid

typedef _Float16 f16x8 __attribute__((ext_vector_type(8)));
typedef float    f32x4 __attribute__((ext_vector_type(4)));

// ---- prep: h->fp16 convert + HH/ZH zero rows + W1/W2 fragment packs + gcnt zero ----
__global__ __launch_bounds__(256) void prep(const float2* __restrict__ hf,
                                            __half2* __restrict__ HH,
                                            __half2* __restrict__ ZH2,
                                            const float* __restrict__ W1,
                                            const float* __restrict__ W2,
                                            f16x8* __restrict__ w1frag,
                                            f16x8* __restrict__ w2frag,
                                            int* __restrict__ gcnt) {
    if (blockIdx.x < 4) {                       // pack W1 -> 1024 frags
        int e = blockIdx.x * 256 + threadIdx.x;
        int l = e & 63, cf = e >> 6;            // cf = ct*2+f
        int f = cf & 1, ct = cf >> 1;
        int kbase = f * 32 + (l >> 4) * 8;
        int c = ct * 16 + (l & 15);
        f16x8 v;
#pragma unroll
        for (int r = 0; r < 8; ++r)
            v[r] = (_Float16)W1[(kbase + r) * H + c];
        w1frag[e] = v;
    } else if (blockIdx.x < 7) {                // pack W2 -> 768 frags (48-col pad)
        int e = (blockIdx.x - 4) * 256 + threadIdx.x;
        int l = e & 63, cf = e >> 6;            // cf = ct*4+kc
        int kc = cf & 3, ct = cf >> 2;
        int kbase = kc * 32 + (l >> 4) * 8;
        int c = ct * 16 + (l & 15);
        f16x8 v;
#pragma unroll
        for (int r = 0; r < 8; ++r)
            v[r] = (c < C) ? (_Float16)W2[(kbase + r) * C + c] : (_Float16)0.f;
        w2frag[e] = v;
    } else if (blockIdx.x == 7 && threadIdx.x < 128) {
        gcnt[threadIdx.x] = 0;
    } else if (blockIdx.x == 8 && threadIdx.x < 32) {
        // HH zero row in half2 units: index N*32 = byte N*128 (what H4[N*16+fl] reads)
        HH[(size_t)N * 32 + threadIdx.x] = __floats2half2_rn(0.f, 0.f);
    } else if (blockIdx.x == 9 && threadIdx.x < 32) {
        // ZH zero row in half2 units: row stride 64 halves = 32 half2
        ZH2[(size_t)N * 32 + threadIdx.x] = __floats2half2_rn(0.f, 0.f);
    }
    for (int i = blockIdx.x * 256 + threadIdx.x; i < N * 32; i += PREPB * 256) {
        float2 p = hf[i];
        HH[i] = __floats2half2_rn(p.x, p.y);
    }
}

// ---- single-pass append: LDS bucket count -> one global atomicAdd per
//      (block,bucket) -> scatter into bucket staging windows ----
__global__ __launch_bounds__(256) void append_d(const int2* __restrict__ edges,
                                                int* __restrict__ gcnt,
                                                int* __restrict__ staging) {
    __shared__ int lcnt[NBUCK2], lbase[NBUCK2];
    int t = threadIdx.x;
    if (t < NBUCK2) lcnt[t] = 0;
    __syncthreads();
    int base = blockIdx.x * EBLK + t * 8;
    int2 ed[8]; int pos[8];
#pragma unroll
    for (int i = 0; i < 8; ++i) {
        int e = base + i;
        if (e < E) {
            ed[i] = edges[e];
            pos[i] = atomicAdd(&lcnt[ed[i].y >> 10], 1);   // LDS atomic
        }
    }
    __syncthreads();
    if (t < NBUCK2 && lcnt[t]) lbase[t] = atomicAdd(&gcnt[t], lcnt[t]);
    __syncthreads();
#pragma unroll
    for (int i = 0; i < 8; ++i) {
        int e = base + i;
        if (e < E) {
            int b = ed[i].y >> 10;
            int p = lbase[b] + pos[i];
            if (p < SCAP)                                   // never in practice
                staging[b * SCAP + p] = (ed[i].x << 10) | (ed[i].y & 1023);
        }
    }
}

// ---- per-bucket: LDS count -> wave-scan of PADDED lengths -> rd, sentinel pad,
//      scatter csr. Node window = x8-padded; pad slots = N (zero row). ----
__global__ __launch_bounds__(1024) void fill_b(const int* __restrict__ staging,
                                               const int* __restrict__ gcnt,
                                               int2* __restrict__ rd,
                                               int* __restrict__ csr) {
    __shared__ int cnt[1024], cur[1024], wtot[16], wbase[16];
    int b = blockIdx.x, t = threadIdx.x;
    cnt[t] = 0;
    __syncthreads();
    int tot = gcnt[b];
    if (tot > SCAP) tot = SCAP;
    int lo_s = b * SCAP;
    for (int i = t; i < tot; i += 1024)
        atomicAdd(&cnt[staging[lo_s + i] & 1023], 1);
    __syncthreads();
    int v = cnt[t];
    int vp = (v + 7) & ~7;                       // padded length
    int lane = t & 63, wid = t >> 6;
    int sv = vp;                                 // inclusive wave scan of vp
#pragma unroll
    for (int off = 1; off < 64; off <<= 1) {
        int x = __shfl_up(sv, off);
        if (lane >= off) sv += x;
    }
    if (lane == 63) wtot[wid] = sv;
    __syncthreads();
    if (t == 0) {
        int run = 0;
#pragma unroll
        for (int i = 0; i < 16; ++i) { wbase[i] = run; run += wtot[i]; }
    }
    __syncthreads();
    int ex = sv - vp + wbase[wid];
    cur[t] = ex;
    int lo_c = b * CCAP;
    int node = (b << 10) + t;
    if (node < N) rd[node] = make_int2(lo_c + ex, v);
    for (int j = v; j < vp; ++j) csr[lo_c + ex + j] = N;   // sentinel pad
    __syncthreads();
    for (int i = t; i < tot; i += 1024) {
        int w = staging[lo_s + i];
        int p = atomicAdd(&cur[w & 1023], 1);
        csr[lo_c + p] = w >> 10;
    }
}

// ---- FUSED layer 1 + gemm2: gather -> LDS -> MFMA1 (XH tile, relu, fp16) ->
//      LDS x2[16][136] -> MFMA2 (ZH tile = XH @ W2pad) -> ZH global.
//      XH never touches HBM. ----
constexpr int X2S = 136;   // x2 LDS stride (halves): 2-way conflict = free
__global__ __launch_bounds__(256) void fused12(const __half2* __restrict__ HH,
                                               const int* __restrict__ csr,
                                               const int2* __restrict__ rd,
                                               const f16x8* __restrict__ w1frag,
                                               const f16x8* __restrict__ w2frag,
                                               const float* __restrict__ b1,
                                               __half* __restrict__ ZH) {
    __shared__ _Float16 a_h[16 * 72] __attribute__((aligned(16)));
    __shared__ _Float16 x2[16 * X2S] __attribute__((aligned(16)));
    int nl = threadIdx.x >> 4;                 // node-local 0..15
    int fl = threadIdx.x & 15;
    int node = blockIdx.x * 16 + nl;
    const float2* H4 = (const float2*)HH;      // row = 16 float2 = 128 B
    int2 rdv = rd[node];
    int rs = rdv.x;
    int dpad = (rdv.y + 7) & ~7;               // x8-padded run length
    float a0, a1, a2, a3;
    {   // self-loop init
        float2 raw = H4[node * 16 + fl];
        const __half2* hp = (const __half2*)&raw;
        float2 v0 = __half22float2(hp[0]), v1 = __half22float2(hp[1]);
        a0 = v0.x; a1 = v0.y; a2 = v1.x; a3 = v1.y;
    }
    for (int j0 = 0; j0 < dpad; j0 += 8) {     // 8 rows in flight, no predication
        int k[8];
#pragma unroll
        for (int t = 0; t < 8; ++t) k[t] = csr[rs + j0 + t];
#pragma unroll
        for (int t = 0; t < 8; ++t) {
            float2 raw = H4[k[t] * 16 + fl];   // sentinel -> zero row (L1-hot)
            const __half2* hp = (const __half2*)&raw;
            float2 v0 = __half22float2(hp[0]), v1 = __half22float2(hp[1]);
            a0 += v0.x; a1 += v0.y; a2 += v1.x; a3 += v1.y;
        }
    }
    *(__half2*)&a_h[nl * 72 + fl * 4]     = __floats2half2_rn(a0, a1);
    *(__half2*)&a_h[nl * 72 + fl * 4 + 2] = __floats2half2_rn(a2, a3);
    __syncthreads();
    // ---- MFMA1: wave wv -> XH col tiles t0=2wv, t1=2wv+1; relu -> fp16 LDS x2 ----
    int wv = threadIdx.x >> 6;
    int l  = threadIdx.x & 63;
    int lg = l >> 4, lr = l & 15;
    {
        f16x8 aA0 = *(const f16x8*)&a_h[lr * 72 + 0 * 32 + lg * 8];
        f16x8 aA1 = *(const f16x8*)&a_h[lr * 72 + 1 * 32 + lg * 8];
        int t0 = wv * 2, t1 = wv * 2 + 1;
        f16x8 b00 = w1frag[(t0 * 2 + 0) * 64 + l];
        f16x8 b01 = w1frag[(t0 * 2 + 1) * 64 + l];
        f16x8 b10 = w1frag[(t1 * 2 + 0) * 64 + l];
        f16x8 b11 = w1frag[(t1 * 2 + 1) * 64 + l];
        f32x4 acc0 = {0.f, 0.f, 0.f, 0.f}, acc1 = {0.f, 0.f, 0.f, 0.f};
        acc0 = __builtin_amdgcn_mfma_f32_16x16x32_f16(aA0, b00, acc0, 0, 0, 0);
        acc0 = __builtin_amdgcn_mfma_f32_16x16x32_f16(aA1, b01, acc0, 0, 0, 0);
        acc1 = __builtin_amdgcn_mfma_f32_16x16x32_f16(aA0, b10, acc1, 0, 0, 0);
        acc1 = __builtin_amdgcn_mfma_f32_16x16x32_f16(aA1, b11, acc1, 0, 0, 0);
        // D col = lane&15, row = (lane>>4)*4 + r (verified layout)
        int c0 = t0 * 16 + lr, c1 = t1 * 16 + lr;
        float bias0 = b1[c0], bias1 = b1[c1];
#pragma unroll
        for (int r = 0; r < 4; ++r) {
            int row = lg * 4 + r;              // block-local XH row
            x2[row * X2S + c0] = (_Float16)__float2half_rn(fmaxf(acc0[r] + bias0, 0.f));
            x2[row * X2S + c1] = (_Float16)__float2half_rn(fmaxf(acc1[r] + bias1, 0.f));
        }
    }
    __syncthreads();
    // ---- MFMA2: waves 0..2 -> ZH col tile ct=wv (16 cols, K=128, 4 MFMAs) ----
    if (wv < 3) {
        f16x8 a2f[4];
#pragma unroll
        for (int kc = 0; kc < 4; ++kc)
            a2f[kc] = *(const f16x8*)&x2[lr * X2S + kc * 32 + lg * 8];
        f32x4 acc = {0.f, 0.f, 0.f, 0.f};
#pragma unroll
        for (int kc = 0; kc < 4; ++kc)
            acc = __builtin_amdgcn_mfma_f32_16x16x32_f16(a2f[kc],
                      w2frag[(wv * 4 + kc) * 64 + l], acc, 0, 0, 0);
        int col = wv * 16 + lr;
        if (col < C) {
            int row0 = blockIdx.x * 16;
#pragma unroll
            for (int r = 0; r < 4; ++r) {
                int row = row0 + lg * 4 + r;
                ZH[(size_t)row * 64 + col] = __float2half_rn(acc[r]);
            }
        }
    }
}

// ---- out[node] = softmax(Z[node] + sum Z[src] + b2): 128B-aligned rows,
//      only the 10 real lanes load; predication-free batch-8 via sentinel ----
__global__ __launch_bounds__(256) void gather2_softmax(const __half2* __restrict__ ZH,
                                                       const int* __restrict__ csr,
                                                       const int2* __restrict__ rd,
                                                       const float* __restrict__ b2,
                                                       float4* __restrict__ out) {
    int node = blockIdx.x * 16 + (threadIdx.x >> 4);
    int fl = threadIdx.x & 15;
    const float2* Z4 = (const float2*)ZH;     // row = 16 float2 = 128 B
    int2 rdv = rd[node];
    int rs = rdv.x;
    int dpad = (rdv.y + 7) & ~7;
    bool real = fl < 10;
    float a0 = 0.f, a1 = 0.f, a2 = 0.f, a3 = 0.f;
    if (real) {   // self-loop init
        float2 raw = Z4[node * 16 + fl];
        const __half2* hp = (const __half2*)&raw;
        float2 v0 = __half22float2(hp[0]), v1 = __half22float2(hp[1]);
        a0 = v0.x; a1 = v0.y; a2 = v1.x; a3 = v1.y;
    }
    for (int j0 = 0; j0 < dpad; j0 += 8) {
        int k[8];
#pragma unroll
        for (int t = 0; t < 8; ++t) k[t] = csr[rs + j0 + t];
        if (real) {
#pragma unroll
            for (int t = 0; t < 8; ++t) {
                float2 raw = Z4[k[t] * 16 + fl];   // sentinel -> zero row
                const __half2* hp = (const __half2*)&raw;
                float2 v0 = __half22float2(hp[0]), v1 = __half22float2(hp[1]);
                a0 += v0.x; a1 += v0.y; a2 += v1.x; a3 += v1.y;
            }
        }
    }
    // softmax over the 40 real cols (lanes fl<10, cols 4fl..4fl+3)
    const float4* b4 = (const float4*)b2;
    float4 bb = b4[real ? fl : 9];
    float v0 = real ? a0 + bb.x : -INFINITY;
    float v1 = real ? a1 + bb.y : -INFINITY;
    float v2 = real ? a2 + bb.z : -INFINITY;
    float v3 = real ? a3 + bb.w : -INFINITY;
    float m = fmaxf(fmaxf(v0, v1), fmaxf(v2, v3));
#pragma unroll
    for (int off = 1; off < 16; off <<= 1) m = fmaxf(m, __shfl_xor(m, off));
    float e0 = __expf(v0 - m), e1 = __expf(v1 - m);   // -inf lanes -> exp = 0
    float e2 = __expf(v2 - m), e3 = __expf(v3 - m);
    float s = (e0 + e1) + (e2 + e3);
#pragma unroll
    for (int off = 1; off < 16; off <<= 1) s += __shfl_xor(s, off);
    float inv = 1.f / s;
    if (real)
        out[node * 10 + fl] = make_float4(e0 * inv, e1 * inv, e2 * inv, e3 * inv);
}

extern "C" void kernel_launch(void* const* d_in, const int* in_sizes, int n_in,
                              void* d_out, int out_size, void* d_ws, size_t ws_size,
                              hipStream_t stream) {
    const float* h   = (const float*)d_in[0];   // N*D
    const int*   adj = (const int*)  d_in[1];   // E*2
    const float* W1  = (const float*)d_in[2];   // D*H
    const float* b1  = (const float*)d_in[3];   // H
    const float* W2  = (const float*)d_in[4];   // H*C
    const float* b2  = (const float*)d_in[5];   // C
    float* out = (float*)d_out;                 // N*C fp32

    // workspace (~41 MB), NO aliasing (XH deleted):
    //   w1frag 16KB | w2frag 12KB | HH (N+1)*64 | ZH (N+1)*64 |
    //   gcnt 128 | staging 98*16384 | csr 98*20480 | rd N int2
    f16x8*  w1frag = (f16x8*)d_ws;                       // 1024 x 16 B
    f16x8*  w2frag = w1frag + 1024;                      // 768 x 16 B
    __half* HH = (__half*)(w2frag + 768);                // (N+1)*64 fp16
    __half* ZH = HH + (size_t)(N + 1) * 64;              // (N+1)*64 fp16
    int* gcnt    = (int*)(ZH + (size_t)(N + 1) * 64);    // 128
    int* staging = gcnt + 128;                           // NBUCK2*SCAP
    int* csr     = staging + NBUCK2 * SCAP;              // NBUCK2*CCAP
    int2* rd     = (int2*)(csr + NBUCK2 * CCAP);         // N (row_start, deg)

    prep     <<<PREPB, 256, 0, stream>>>((const float2*)h, (__half2*)HH,
                                         (__half2*)ZH, W1, W2, w1frag, w2frag, gcnt);
    append_d <<<NHB, 256, 0, stream>>>((const int2*)adj, gcnt, staging);
    fill_b   <<<NBUCK2, 1024, 0, stream>>>(staging, gcnt, rd, csr);

    fused12        <<<N / 16, 256, 0, stream>>>((const __half2*)HH, csr, rd,
                                                w1frag, w2frag, b1, ZH);
    gather2_softmax<<<N / 16, 256, 0, stream>>>((const __half2*)ZH, csr, rd,
                                                b2, (float4*)out);
}

// Round 14
// 178.865 us; speedup vs baseline: 1.0837x; 1.0012x over previous
//
#include <hip/hip_runtime.h>
#include <hip/hip_fp16.h>
#include <math.h>

// GCN: out = softmax( S·relu((S·h)W1 + b1) · W2 + b2 ),  S = in-edge sum + self-loop.
// Round 24: R23 (best, 179.1us) + prep MERGED into append_d (-> append_conv):
// h->fp16 conversion / W1,W2 frag packs / zero rows are independent of the edge
// pass, so they ride along in the same 586-block kernel (packs in blocks 0..6,
// zero rows in blocks 8..9, conversion grid-strided everywhere). gcnt zeroing
// moves to a 512B hipMemsetAsync (graph-capture-safe). Launches 5 -> 4 (+memset),
// and the 38MB conversion overlaps the 9.6MB edge pass instead of serializing.

constexpr int N = 100000;
constexpr int E = 1200000;
constexpr int D = 64;    // input dim
constexpr int H = 128;   // hidden
constexpr int C = 40;    // classes
constexpr int NBUCK2 = 98;                      // buckets of 1024 dst nodes
constexpr int EBLK   = 2048;                    // edges per append block
constexpr int NHB    = (E + EBLK - 1) / EBLK;   // 586 edge blocks
constexpr int SCAP   = 16384;                   // staging capacity per bucket
constexpr int CCAP   = 20480;                   // csr capacity per bucket (padded)

typedef _Float16 f16x8 __attribute__((ext_vector_type(8)));
typedef float    f32x4 __attribute__((ext_vector_type(4)));

// ---- merged: single-pass edge append + h->fp16 convert + frag packs + zero rows.
//      gcnt is pre-zeroed by hipMemsetAsync before this kernel. ----
__global__ __launch_bounds__(256) void append_conv(const int2* __restrict__ edges,
                                                   int* __restrict__ gcnt,
                                                   int* __restrict__ staging,
                                                   const float2* __restrict__ hf,
                                                   __half2* __restrict__ HH,
                                                   __half2* __restrict__ ZH2,
                                                   const float* __restrict__ W1,
                                                   const float* __restrict__ W2,
                                                   f16x8* __restrict__ w1frag,
                                                   f16x8* __restrict__ w2frag) {
    __shared__ int lcnt[NBUCK2], lbase[NBUCK2];
    int t = threadIdx.x;
    if (t < NBUCK2) lcnt[t] = 0;
    // ---- side work (independent of the edge pass) ----
    if (blockIdx.x < 4) {                       // pack W1 -> 1024 frags
        int e = blockIdx.x * 256 + t;
        int l = e & 63, cf = e >> 6;            // cf = ct*2+f
        int f = cf & 1, ct = cf >> 1;
        int kbase = f * 32 + (l >> 4) * 8;
        int c = ct * 16 + (l & 15);
        f16x8 v;
#pragma unroll
        for (int r = 0; r < 8; ++r)
            v[r] = (_Float16)W1[(kbase + r) * H + c];
        w1frag[e] = v;
    } else if (blockIdx.x < 7) {                // pack W2 -> 768 frags (48-col pad)
        int e = (blockIdx.x - 4) * 256 + t;
        int l = e & 63, cf = e >> 6;            // cf = ct*4+kc
        int kc = cf & 3, ct = cf >> 2;
        int kbase = kc * 32 + (l >> 4) * 8;
        int c = ct * 16 + (l & 15);
        f16x8 v;
#pragma unroll
        for (int r = 0; r < 8; ++r)
            v[r] = (c < C) ? (_Float16)W2[(kbase + r) * C + c] : (_Float16)0.f;
        w2frag[e] = v;
    } else if (blockIdx.x == 8 && t < 32) {
        // HH zero row in half2 units: index N*32 = byte N*128 (what H4[N*16+fl] reads)
        HH[(size_t)N * 32 + t] = __floats2half2_rn(0.f, 0.f);
    } else if (blockIdx.x == 9 && t < 32) {
        // ZH zero row in half2 units: row stride 64 halves = 32 half2
        ZH2[(size_t)N * 32 + t] = __floats2half2_rn(0.f, 0.f);
    }
    // h -> fp16 convert, grid-strided over all NHB blocks
    for (int i = blockIdx.x * 256 + t; i < N * 32; i += NHB * 256) {
        float2 p = hf[i];
        HH[i] = __floats2half2_rn(p.x, p.y);
    }
    __syncthreads();
    // ---- edge pass: LDS bucket count -> one global atomicAdd per (block,bucket)
    //      -> scatter into bucket staging windows ----
    int base = blockIdx.x * EBLK + t * 8;
    int2 ed[8]; int pos[8];
#pragma unroll
    for (int i = 0; i < 8; ++i) {
        int e = base + i;
        if (e < E) {
            ed[i] = edges[e];
            pos[i] = atomicAdd(&lcnt[ed[i].y >> 10], 1);   // LDS atomic
        }
    }
    __syncthreads();
    if (t < NBUCK2 && lcnt[t]) lbase[t] = atomicAdd(&gcnt[t], lcnt[t]);
    __syncthreads();
#pragma unroll
    for (int i = 0; i < 8; ++i) {
        int e = base + i;
        if (e < E) {
            int b = ed[i].y >> 10;
            int p = lbase[b] + pos[i];
            if (p < SCAP)                                   // never in practice
                staging[b * SCAP + p] = (ed[i].x << 10) | (ed[i].y & 1023);
        }
    }
}

// ---- per-bucket: LDS count -> wave-scan of PADDED lengths -> rd, sentinel pad,
//      scatter csr. Node window = x8-padded; pad slots = N (zero row). ----
__global__ __launch_bounds__(1024) void fill_b(const int* __restrict__ staging,
                                               const int* __restrict__ gcnt,
                                               int2* __restrict__ rd,
                                               int* __restrict__ csr) {
    __shared__ int cnt[1024], cur[1024], wtot[16], wbase[16];
    int b = blockIdx.x, t = threadIdx.x;
    cnt[t] = 0;
    __syncthreads();
    int tot = gcnt[b];
    if (tot > SCAP) tot = SCAP;
    int lo_s = b * SCAP;
    for (int i = t; i < tot; i += 1024)
        atomicAdd(&cnt[staging[lo_s + i] & 1023], 1);
    __syncthreads();
    int v = cnt[t];
    int vp = (v + 7) & ~7;                       // padded length
    int lane = t & 63, wid = t >> 6;
    int sv = vp;                                 // inclusive wave scan of vp
#pragma unroll
    for (int off = 1; off < 64; off <<= 1) {
        int x = __shfl_up(sv, off);
        if (lane >= off) sv += x;
    }
    if (lane == 63) wtot[wid] = sv;
    __syncthreads();
    if (t == 0) {
        int run = 0;
#pragma unroll
        for (int i = 0; i < 16; ++i) { wbase[i] = run; run += wtot[i]; }
    }
    __syncthreads();
    int ex = sv - vp + wbase[wid];
    cur[t] = ex;
    int lo_c = b * CCAP;
    int node = (b << 10) + t;
    if (node < N) rd[node] = make_int2(lo_c + ex, v);
    for (int j = v; j < vp; ++j) csr[lo_c + ex + j] = N;   // sentinel pad
    __syncthreads();
    for (int i = t; i < tot; i += 1024) {
        int w = staging[lo_s + i];
        int p = atomicAdd(&cur[w & 1023], 1);
        csr[lo_c + p] = w >> 10;
    }
}

// ---- FUSED layer 1 + gemm2: gather -> LDS -> MFMA1 (XH tile, relu, fp16) ->
//      LDS x2[16][136] -> MFMA2 (ZH tile = XH @ W2pad) -> ZH global.
//      XH never touches HBM. ----
constexpr int X2S = 136;   // x2 LDS stride (halves): 2-way conflict = free
__global__ __launch_bounds__(256) void fused12(const __half2* __restrict__ HH,
                                               const int* __restrict__ csr,
                                               const int2* __restrict__ rd,
                                               const f16x8* __restrict__ w1frag,
                                               const f16x8* __restrict__ w2frag,
                                               const float* __restrict__ b1,
                                               __half* __restrict__ ZH) {
    __shared__ _Float16 a_h[16 * 72] __attribute__((aligned(16)));
    __shared__ _Float16 x2[16 * X2S] __attribute__((aligned(16)));
    int nl = threadIdx.x >> 4;                 // node-local 0..15
    int fl = threadIdx.x & 15;
    int node = blockIdx.x * 16 + nl;
    const float2* H4 = (const float2*)HH;      // row = 16 float2 = 128 B
    int2 rdv = rd[node];
    int rs = rdv.x;
    int dpad = (rdv.y + 7) & ~7;               // x8-padded run length
    float a0, a1, a2, a3;
    {   // self-loop init
        float2 raw = H4[node * 16 + fl];
        const __half2* hp = (const __half2*)&raw;
        float2 v0 = __half22float2(hp[0]), v1 = __half22float2(hp[1]);
        a0 = v0.x; a1 = v0.y; a2 = v1.x; a3 = v1.y;
    }
    for (int j0 = 0; j0 < dpad; j0 += 8) {     // 8 rows in flight, no predication
        int k[8];
#pragma unroll
        for (int t = 0; t < 8; ++t) k[t] = csr[rs + j0 + t];
#pragma unroll
        for (int t = 0; t < 8; ++t) {
            float2 raw = H4[k[t] * 16 + fl];   // sentinel -> zero row (L1-hot)
            const __half2* hp = (const __half2*)&raw;
            float2 v0 = __half22float2(hp[0]), v1 = __half22float2(hp[1]);
            a0 += v0.x; a1 += v0.y; a2 += v1.x; a3 += v1.y;
        }
    }
    *(__half2*)&a_h[nl * 72 + fl * 4]     = __floats2half2_rn(a0, a1);
    *(__half2*)&a_h[nl * 72 + fl * 4 + 2] = __floats2half2_rn(a2, a3);
    __syncthreads();
    // ---- MFMA1: wave wv -> XH col tiles t0=2wv, t1=2wv+1; relu -> fp16 LDS x2 ----
    int wv = threadIdx.x >> 6;
    int l  = threadIdx.x & 63;
    int lg = l >> 4, lr = l & 15;
    {
        f16x8 aA0 = *(const f16x8*)&a_h[lr * 72 + 0 * 32 + lg * 8];
        f16x8 aA1 = *(const f16x8*)&a_h[lr * 72 + 1 * 32 + lg * 8];
        int t0 = wv * 2, t1 = wv * 2 + 1;
        f16x8 b00 = w1frag[(t0 * 2 + 0) * 64 + l];
        f16x8 b01 = w1frag[(t0 * 2 + 1) * 64 + l];
        f16x8 b10 = w1frag[(t1 * 2 + 0) * 64 + l];
        f16x8 b11 = w1frag[(t1 * 2 + 1) * 64 + l];
        f32x4 acc0 = {0.f, 0.f, 0.f, 0.f}, acc1 = {0.f, 0.f, 0.f, 0.f};
        acc0 = __builtin_amdgcn_mfma_f32_16x16x32_f16(aA0, b00, acc0, 0, 0, 0);
        acc0 = __builtin_amdgcn_mfma_f32_16x16x32_f16(aA1, b01, acc0, 0, 0, 0);
        acc1 = __builtin_amdgcn_mfma_f32_16x16x32_f16(aA0, b10, acc1, 0, 0, 0);
        acc1 = __builtin_amdgcn_mfma_f32_16x16x32_f16(aA1, b11, acc1, 0, 0, 0);
        // D col = lane&15, row = (lane>>4)*4 + r (verified layout)
        int c0 = t0 * 16 + lr, c1 = t1 * 16 + lr;
        float bias0 = b1[c0], bias1 = b1[c1];
#pragma unroll
        for (int r = 0; r < 4; ++r) {
            int row = lg * 4 + r;              // block-local XH row
            x2[row * X2S + c0] = (_Float16)__float2half_rn(fmaxf(acc0[r] + bias0, 0.f));
            x2[row * X2S + c1] = (_Float16)__float2half_rn(fmaxf(acc1[r] + bias1, 0.f));
        }
    }
    __syncthreads();
    // ---- MFMA2: waves 0..2 -> ZH col tile ct=wv (16 cols, K=128, 4 MFMAs) ----
    if (wv < 3) {
        f16x8 a2f[4];
#pragma unroll
        for (int kc = 0; kc < 4; ++kc)
            a2f[kc] = *(const f16x8*)&x2[lr * X2S + kc * 32 + lg * 8];
        f32x4 acc = {0.f, 0.f, 0.f, 0.f};
#pragma unroll
        for (int kc = 0; kc < 4; ++kc)
            acc = __builtin_amdgcn_mfma_f32_16x16x32_f16(a2f[kc],
                      w2frag[(wv * 4 + kc) * 64 + l], acc, 0, 0, 0);
        int col = wv * 16 + lr;
        if (col < C) {
            int row0 = blockIdx.x * 16;
#pragma unroll
            for (int r = 0; r < 4; ++r) {
                int row = row0 + lg * 4 + r;
                ZH[(size_t)row * 64 + col] = __float2half_rn(acc[r]);
            }
        }
    }
}

// ---- out[node] = softmax(Z[node] + sum Z[src] + b2): 128B-aligned rows,
//      only the 10 real lanes load; predication-free batch-8 via sentinel ----
__global__ __launch_bounds__(256) void gather2_softmax(const __half2* __restrict__ ZH,
                                                       const int* __restrict__ csr,
                                                       const int2* __restrict__ rd,
                                                       const float* __restrict__ b2,
                                                       float4* __restrict__ out) {
    int node = blockIdx.x * 16 + (threadIdx.x >> 4);
    int fl = threadIdx.x & 15;
    const float2* Z4 = (const float2*)ZH;     // row = 16 float2 = 128 B
    int2 rdv = rd[node];
    int rs = rdv.x;
    int dpad = (rdv.y + 7) & ~7;
    bool real = fl < 10;
    float a0 = 0.f, a1 = 0.f, a2 = 0.f, a3 = 0.f;
    if (real) {   // self-loop init
        float2 raw = Z4[node * 16 + fl];
        const __half2* hp = (const __half2*)&raw;
        float2 v0 = __half22float2(hp[0]), v1 = __half22float2(hp[1]);
        a0 = v0.x; a1 = v0.y; a2 = v1.x; a3 = v1.y;
    }
    for (int j0 = 0; j0 < dpad; j0 += 8) {
        int k[8];
#pragma unroll
        for (int t = 0; t < 8; ++t) k[t] = csr[rs + j0 + t];
        if (real) {
#pragma unroll
            for (int t = 0; t < 8; ++t) {
                float2 raw = Z4[k[t] * 16 + fl];   // sentinel -> zero row
                const __half2* hp = (const __half2*)&raw;
                float2 v0 = __half22float2(hp[0]), v1 = __half22float2(hp[1]);
                a0 += v0.x; a1 += v0.y; a2 += v1.x; a3 += v1.y;
            }
        }
    }
    // softmax over the 40 real cols (lanes fl<10, cols 4fl..4fl+3)
    const float4* b4 = (const float4*)b2;
    float4 bb = b4[real ? fl : 9];
    float v0 = real ? a0 + bb.x : -INFINITY;
    float v1 = real ? a1 + bb.y : -INFINITY;
    float v2 = real ? a2 + bb.z : -INFINITY;
    float v3 = real ? a3 + bb.w : -INFINITY;
    float m = fmaxf(fmaxf(v0, v1), fmaxf(v2, v3));
#pragma unroll
    for (int off = 1; off < 16; off <<= 1) m = fmaxf(m, __shfl_xor(m, off));
    float e0 = __expf(v0 - m), e1 = __expf(v1 - m);   // -inf lanes -> exp = 0
    float e2 = __expf(v2 - m), e3 = __expf(v3 - m);
    float s = (e0 + e1) + (e2 + e3);
#pragma unroll
    for (int off = 1; off < 16; off <<= 1) s += __shfl_xor(s, off);
    float inv = 1.f / s;
    if (real)
        out[node * 10 + fl] = make_float4(e0 * inv, e1 * inv, e2 * inv, e3 * inv);
}

extern "C" void kernel_launch(void* const* d_in, const int* in_sizes, int n_in,
                              void* d_out, int out_size, void* d_ws, size_t ws_size,
                              hipStream_t stream) {
    const float* h   = (const float*)d_in[0];   // N*D
    const int*   adj = (const int*)  d_in[1];   // E*2
    const float* W1  = (const float*)d_in[2];   // D*H
    const float* b1  = (const float*)d_in[3];   // H
    const float* W2  = (const float*)d_in[4];   // H*C
    const float* b2  = (const float*)d_in[5];   // C
    float* out = (float*)d_out;                 // N*C fp32

    // workspace (~41 MB), NO aliasing:
    //   w1frag 16KB | w2frag 12KB | HH (N+1)*64 | ZH (N+1)*64 |
    //   gcnt 128 | staging 98*16384 | csr 98*20480 | rd N int2
    f16x8*  w1frag = (f16x8*)d_ws;                       // 1024 x 16 B
    f16x8*  w2frag = w1frag + 1024;                      // 768 x 16 B
    __half* HH = (__half*)(w2frag + 768);                // (N+1)*64 fp16
    __half* ZH = HH + (size_t)(N + 1) * 64;              // (N+1)*64 fp16
    int* gcnt    = (int*)(ZH + (size_t)(N + 1) * 64);    // 128
    int* staging = gcnt + 128;                           // NBUCK2*SCAP
    int* csr     = staging + NBUCK2 * SCAP;              // NBUCK2*CCAP
    int2* rd     = (int2*)(csr + NBUCK2 * CCAP);         // N (row_start, deg)

    hipMemsetAsync(gcnt, 0, 128 * sizeof(int), stream);
    append_conv<<<NHB, 256, 0, stream>>>((const int2*)adj, gcnt, staging,
                                         (const float2*)h, (__half2*)HH,
                                         (__half2*)ZH, W1, W2, w1frag, w2frag);
    fill_b     <<<NBUCK2, 1024, 0, stream>>>(staging, gcnt, rd, csr);

    fused12        <<<N / 16, 256, 0, stream>>>((const __half2*)HH, csr, rd,
                                                w1frag, w2frag, b1, ZH);
    gather2_softmax<<<N / 16, 256, 0, stream>>>((const __half2*)ZH, csr, rd,
                                                b2, (float4*)out);
}